// Round 5
// baseline (111.032 us; speedup 1.0000x reference)
//
#include <hip/hip_runtime.h>
#include <math.h>

// NoisyTopKRouter via f16 2-limb (Markidis) 3-pass MFMA.
// Round 5: NO LDS / NO barriers in main loop. Each wave owns 16 tokens x 64
// cols; A-fragments loaded per-wave directly from global x (L1 catches the
// 2x duplication), B direct from L2-resident wt limbs. Explicit 2-deep A /
// 1-deep B register pipeline. One __syncthreads before the top-2 epilogue.

typedef _Float16 f16;
typedef _Float16 f16x8 __attribute__((ext_vector_type(8)));
typedef float    f32x4 __attribute__((ext_vector_type(4)));

#define NEMBD 2048
#define NEXP  64
#define BM    32              // tokens per block (2 row-groups x 16)
#define NCH   64              // K chunks of 32
#define WSCALE 64.0f
#define INV_WSCALE 0.015625f

union F4H8 { float4 f; f16x8 h; };

__device__ __forceinline__ f16x8 ld16h(const f16* p) {
    F4H8 u; u.f = *(const float4*)p; return u.h;
}

// ---------- kernel 0: W -> transposed, x64-scaled f16 limbs ----------
// wt layout per limb: [chunk 64][n 128][k 32] f16 (n: 0..63 route, 64..127 noise)
__global__ __launch_bounds__(256) void build_wt(
    const float* __restrict__ Wr, const float* __restrict__ Wn,
    f16* __restrict__ wt_hi, f16* __restrict__ wt_lo)
{
    __shared__ float ws[32][129];
    const int c = blockIdx.x, t = threadIdx.x;
    const int k0 = c * 32;
    {
        const int k  = t >> 3;
        const int n8 = (t & 7) << 3;
        const float* s0 = Wr + (size_t)(k0 + k) * NEXP + n8;
        const float* s1 = Wn + (size_t)(k0 + k) * NEXP + n8;
        #pragma unroll
        for (int j = 0; j < 8; ++j) ws[k][n8 + j] = s0[j];
        #pragma unroll
        for (int j = 0; j < 8; ++j) ws[k][64 + n8 + j] = s1[j];
    }
    __syncthreads();
    {
        const int n  = t >> 1;           // 0..127
        const int kh = (t & 1) << 4;     // 0 or 16
        f16x8 hv0, hv1, lv0, lv1;
        #pragma unroll
        for (int j = 0; j < 8; ++j) {
            const float v = ws[kh + j][n] * WSCALE;
            const f16 h = (f16)v;
            hv0[j] = h; lv0[j] = (f16)(v - (float)h);
        }
        #pragma unroll
        for (int j = 0; j < 8; ++j) {
            const float v = ws[kh + 8 + j][n] * WSCALE;
            const f16 h = (f16)v;
            hv1[j] = h; lv1[j] = (f16)(v - (float)h);
        }
        const size_t base = ((size_t)c * 128 + n) * 32 + kh;
        *(f16x8*)(wt_hi + base)     = hv0;
        *(f16x8*)(wt_hi + base + 8) = hv1;
        *(f16x8*)(wt_lo + base)     = lv0;
        *(f16x8*)(wt_lo + base + 8) = lv1;
    }
}

// ---------- kernel 1: fused MFMA router, barrier-free main loop ----------
// 256 threads = 4 waves; wave w: rows (w&1)*16, cols (w>>1)*64. grid = T/32.
__global__ __launch_bounds__(256, 2) void router_fused3(
    const float* __restrict__ x, const float* __restrict__ eps,
    const f16* __restrict__ wt_hi, const f16* __restrict__ wt_lo,
    const float* __restrict__ br, const float* __restrict__ bn,
    float* __restrict__ out_r, float* __restrict__ out_idx)
{
    __shared__ __align__(16) float smem[4352];   // LG[128][33] + TK[4][32]
    float* LG = smem;
    float* TK = smem + 128 * 33;

    const int tid  = threadIdx.x;
    const int lane = tid & 63;
    const int w    = tid >> 6;
    const int wr   = w & 1;          // row group
    const int wc   = w >> 1;         // col group (0: route, 1: noise)
    const int m0   = blockIdx.x * BM;

    const int row16 = lane & 15;
    const int kgrp  = (lane >> 4) << 3;          // 0,8,16,24
    const float* asrc = x + (size_t)(m0 + wr * 16 + row16) * NEMBD + kgrp;

    const int bc    = wc * 64 + row16;
    const int boff0 = (bc +  0) * 32 + kgrp;
    const int boff1 = (bc + 16) * 32 + kgrp;
    const int boff2 = (bc + 32) * 32 + kgrp;
    const int boff3 = (bc + 48) * 32 + kgrp;

    f32x4 acc0 = {0.f,0.f,0.f,0.f}, acc1 = {0.f,0.f,0.f,0.f};
    f32x4 acc2 = {0.f,0.f,0.f,0.f}, acc3 = {0.f,0.f,0.f,0.f};

#define ALOAD(A0, A1, c) do { \
    A0 = *(const float4*)(asrc + (size_t)(c) * 32); \
    A1 = *(const float4*)(asrc + (size_t)(c) * 32 + 4); } while (0)

#define BLOAD(S, c) do { const size_t cb = (size_t)(c) * 4096; \
    S##h0 = ld16h(wt_hi + cb + boff0); S##h1 = ld16h(wt_hi + cb + boff1); \
    S##h2 = ld16h(wt_hi + cb + boff2); S##h3 = ld16h(wt_hi + cb + boff3); \
    S##l0 = ld16h(wt_lo + cb + boff0); S##l1 = ld16h(wt_lo + cb + boff1); \
    S##l2 = ld16h(wt_lo + cb + boff2); S##l3 = ld16h(wt_lo + cb + boff3); } while (0)

#define SPLIT(A0, A1, ah, al) do { \
    const float av[8] = {A0.x, A0.y, A0.z, A0.w, A1.x, A1.y, A1.z, A1.w}; \
    _Pragma("unroll") \
    for (int j = 0; j < 8; ++j) { \
        const f16 h = (f16)av[j]; ah[j] = h; al[j] = (f16)(av[j] - (float)h); } \
    } while (0)

#define MFMA3(A, ah, al, bh, bl) do { \
    A = __builtin_amdgcn_mfma_f32_16x16x32_f16(ah, bh, A, 0, 0, 0); \
    A = __builtin_amdgcn_mfma_f32_16x16x32_f16(al, bh, A, 0, 0, 0); \
    A = __builtin_amdgcn_mfma_f32_16x16x32_f16(ah, bl, A, 0, 0, 0); } while (0)

#define COMPUTE(S, ah, al) do { \
    MFMA3(acc0, ah, al, S##h0, S##l0); \
    MFMA3(acc1, ah, al, S##h1, S##l1); \
    MFMA3(acc2, ah, al, S##h2, S##l2); \
    MFMA3(acc3, ah, al, S##h3, S##l3); } while (0)

    float4 xa0, xa1, xb0, xb1;
    f16x8 pAh0, pAh1, pAh2, pAh3, pAl0, pAl1, pAl2, pAl3;
    f16x8 pBh0, pBh1, pBh2, pBh3, pBl0, pBl1, pBl2, pBl3;
    f16x8 ah, al;

    // prologue: A(0),A(1) raw in regs (2-deep); B(0) in regs (1-deep)
    ALOAD(xa0, xa1, 0);
    ALOAD(xb0, xb1, 1);
    BLOAD(pA, 0);

    // steady state: chunks 0..59 (A issued 2 ahead, B 1 ahead)
    for (int c = 0; c < NCH - 4; c += 2) {
        SPLIT(xa0, xa1, ah, al);
        ALOAD(xa0, xa1, c + 2);
        BLOAD(pB, c + 1);
        COMPUTE(pA, ah, al);
        SPLIT(xb0, xb1, ah, al);
        ALOAD(xb0, xb1, c + 3);
        BLOAD(pA, c + 2);
        COMPUTE(pB, ah, al);
    }
    // chunks 60..63 (no OOB issues)
    SPLIT(xa0, xa1, ah, al);
    ALOAD(xa0, xa1, 62);
    BLOAD(pB, 61);
    COMPUTE(pA, ah, al);
    SPLIT(xb0, xb1, ah, al);
    ALOAD(xb0, xb1, 63);
    BLOAD(pA, 62);
    COMPUTE(pB, ah, al);
    SPLIT(xa0, xa1, ah, al);
    BLOAD(pB, 63);
    COMPUTE(pA, ah, al);
    SPLIT(xb0, xb1, ah, al);
    COMPUTE(pB, ah, al);

#undef ALOAD
#undef BLOAD
#undef SPLIT
#undef MFMA3
#undef COMPUTE

    // ---- epilogue: descale + bias, logits -> LDS ----
    #pragma unroll
    for (int t = 0; t < 4; ++t) {
        const int col = wc * 64 + t * 16 + row16;
        const float bias = (col < NEXP) ? br[col] : bn[col - NEXP];
        const int tokb = wr * 16 + ((lane >> 4) << 2);
        const f32x4 a = (t == 0) ? acc0 : (t == 1) ? acc1 : (t == 2) ? acc2 : acc3;
        #pragma unroll
        for (int r = 0; r < 4; ++r)
            LG[col * 33 + tokb + r] = a[r] * INV_WSCALE + bias;
    }
    __syncthreads();

    // ---- top-2: 2 lanes per token, each scans 32 experts, shfl merge ----
    if (tid < 64) {
        const int t = tid >> 1;
        const int h = tid & 1;
        const float* ep = eps + (size_t)(m0 + t) * NEXP;
        float v1 = -1e30f, v2 = -1e30f;
        int i1 = 0, i2 = 0;
        for (int j = 0; j < 32; ++j) {
            const int e = h * 32 + j;
            const float r  = LG[e * 33 + t];
            const float nr = LG[(NEXP + e) * 33 + t];
            const float sp = fmaxf(nr, 0.f) + log1pf(expf(-fabsf(nr)));
            const float noisy = fmaf(ep[e], sp, r);
            if (noisy > v1) { v2 = v1; i2 = i1; v1 = noisy; i1 = e; }
            else if (noisy > v2) { v2 = noisy; i2 = e; }
        }
        const float ov1 = __shfl_xor(v1, 1);
        const float ov2 = __shfl_xor(v2, 1);
        const int   oi1 = __shfl_xor(i1, 1);
        const int   oi2 = __shfl_xor(i2, 1);
        // a = experts 0..31 half, b = 32..63 half; ties prefer lower index
        float a1, a2, bb1, bb2; int ai1, ai2, bj1, bj2;
        if (h) { a1 = ov1; a2 = ov2; ai1 = oi1; ai2 = oi2; bb1 = v1;  bb2 = v2;  bj1 = i1;  bj2 = i2; }
        else   { a1 = v1;  a2 = v2;  ai1 = i1;  ai2 = i2;  bb1 = ov1; bb2 = ov2; bj1 = oi1; bj2 = oi2; }
        float t1, t2; int ti1, ti2;
        if (bb1 > a1) {
            t1 = bb1; ti1 = bj1;
            if (a1 >= bb2) { t2 = a1; ti2 = ai1; } else { t2 = bb2; ti2 = bj2; }
        } else {
            t1 = a1; ti1 = ai1;
            if (bb1 > a2) { t2 = bb1; ti2 = bj1; } else { t2 = a2; ti2 = ai2; }
        }
        if (h == 0) {
            const float e2 = expf(t2 - t1);
            const float p1 = 1.f / (1.f + e2);
            TK[0 * 32 + t] = p1;
            TK[1 * 32 + t] = e2 * p1;
            TK[2 * 32 + t] = (float)ti1;
            TK[3 * 32 + t] = (float)ti2;
        }
    }
    __syncthreads();

    // ---- write r_out coalesced (8 floats/thread) ----
    {
        const int t  = tid >> 3;            // 0..31
        const int c8 = (tid & 7) << 3;      // 0..56
        const float p1 = TK[t], p2 = TK[32 + t];
        const int i1 = (int)TK[64 + t], i2 = (int)TK[96 + t];
        float buf[8];
        #pragma unroll
        for (int jj = 0; jj < 8; ++jj) {
            const int e = c8 + jj;
            buf[jj] = (e == i1) ? p1 : (e == i2) ? p2 : 0.f;
        }
        float* dst = out_r + (size_t)(m0 + t) * NEXP + c8;
        *(float4*)(dst + 0) = *(float4*)(buf + 0);
        *(float4*)(dst + 4) = *(float4*)(buf + 4);
    }
    if (tid < BM) {
        float2 v = make_float2(TK[64 + tid], TK[96 + tid]);
        *(float2*)(out_idx + (size_t)(m0 + tid) * 2) = v;
    }
}

// ---------- fallback: fused f32 kernel (insurance only) ----------
__global__ __launch_bounds__(256) void router_fused_f32(
    const float* __restrict__ x, const float* __restrict__ eps,
    const float* __restrict__ Wr, const float* __restrict__ br,
    const float* __restrict__ Wn, const float* __restrict__ bn,
    float* __restrict__ out_r, float* __restrict__ out_idx)
{
    __shared__ float xs[32][64];
    __shared__ float ws2[32][128];
    __shared__ float lg[128][64];
    __shared__ float tk[4][64];
    const int tid = threadIdx.x;
    const int tx = tid & 15, ty = tid >> 4;
    const int m0 = blockIdx.x * 64;
    float acc[4][8];
    #pragma unroll
    for (int i = 0; i < 4; ++i)
        #pragma unroll
        for (int j = 0; j < 8; ++j) acc[i][j] = 0.f;
    for (int kc = 0; kc < NEMBD; kc += 32) {
        {
            const int tm = tid >> 2, kk = (tid & 3) << 3;
            const float* src = x + (size_t)(m0 + tm) * NEMBD + kc + kk;
            const float4 a = *(const float4*)(src);
            const float4 b = *(const float4*)(src + 4);
            xs[kk+0][tm]=a.x; xs[kk+1][tm]=a.y; xs[kk+2][tm]=a.z; xs[kk+3][tm]=a.w;
            xs[kk+4][tm]=b.x; xs[kk+5][tm]=b.y; xs[kk+6][tm]=b.z; xs[kk+7][tm]=b.w;
        }
        {
            const int kr = tid >> 3, q = tid & 7;
            const float* src = (q < 4)
                ? (Wr + (size_t)(kc + kr) * NEXP + (q << 4))
                : (Wn + (size_t)(kc + kr) * NEXP + ((q - 4) << 4));
            float* dst = &ws2[kr][q << 4];
            #pragma unroll
            for (int j = 0; j < 16; ++j) dst[j] = src[j];
        }
        __syncthreads();
        #pragma unroll
        for (int k = 0; k < 32; ++k) {
            const float4 xv = *(const float4*)&xs[k][ty << 2];
            const float4 wa = *(const float4*)&ws2[k][tx << 3];
            const float4 wb = *(const float4*)&ws2[k][(tx << 3) + 4];
            const float xr[4] = {xv.x, xv.y, xv.z, xv.w};
            const float wcx[8] = {wa.x, wa.y, wa.z, wa.w, wb.x, wb.y, wb.z, wb.w};
            #pragma unroll
            for (int i = 0; i < 4; ++i)
                #pragma unroll
                for (int j = 0; j < 8; ++j)
                    acc[i][j] = fmaf(xr[i], wcx[j], acc[i][j]);
        }
        __syncthreads();
    }
    {
        const int n0 = tx << 3;
        #pragma unroll
        for (int j = 0; j < 8; ++j) {
            const int n = n0 + j;
            const float b = (n < NEXP) ? br[n] : bn[n - NEXP];
            #pragma unroll
            for (int i = 0; i < 4; ++i)
                lg[n][(ty << 2) + i] = acc[i][j] + b;
        }
    }
    __syncthreads();
    if (tid < 64) {
        const int t = tid;
        const float* ep = eps + (size_t)(m0 + t) * NEXP;
        float v1 = -1e30f, v2 = -1e30f; int i1 = 0, i2 = 0;
        for (int e = 0; e < NEXP; ++e) {
            const float r = lg[e][t], nr = lg[NEXP + e][t];
            const float sp = fmaxf(nr, 0.f) + log1pf(expf(-fabsf(nr)));
            const float noisy = fmaf(ep[e], sp, r);
            if (noisy > v1) { v2=v1; i2=i1; v1=noisy; i1=e; }
            else if (noisy > v2) { v2=noisy; i2=e; }
        }
        const float e2 = expf(v2 - v1);
        const float p1 = 1.f / (1.f + e2);
        tk[0][t]=p1; tk[1][t]=e2*p1; tk[2][t]=(float)i1; tk[3][t]=(float)i2;
    }
    __syncthreads();
    {
        const int t = tid >> 2, c = tid & 3;
        const float p1 = tk[0][t], p2 = tk[1][t];
        const int i1 = (int)tk[2][t], i2 = (int)tk[3][t];
        float buf[16];
        #pragma unroll
        for (int j = 0; j < 16; ++j) {
            const int e = (c << 4) + j;
            buf[j] = (e == i1) ? p1 : (e == i2) ? p2 : 0.f;
        }
        float* dst = out_r + (size_t)(m0 + t) * NEXP + (c << 4);
        *(float4*)(dst+0)=*(float4*)(buf+0); *(float4*)(dst+4)=*(float4*)(buf+4);
        *(float4*)(dst+8)=*(float4*)(buf+8); *(float4*)(dst+12)=*(float4*)(buf+12);
    }
    if (tid < 64) {
        float2 v = make_float2(tk[2][tid], tk[3][tid]);
        *(float2*)(out_idx + (size_t)(m0 + tid) * 2) = v;
    }
}

extern "C" void kernel_launch(void* const* d_in, const int* in_sizes, int n_in,
                              void* d_out, int out_size, void* d_ws, size_t ws_size,
                              hipStream_t stream) {
    const float* x  = (const float*)d_in[0];
    const float* ep = (const float*)d_in[1];
    const float* Wr = (const float*)d_in[2];
    const float* br = (const float*)d_in[3];
    const float* Wn = (const float*)d_in[4];
    const float* bn = (const float*)d_in[5];

    const int T = in_sizes[1] / NEXP;
    float* out_r   = (float*)d_out;
    float* out_idx = (float*)d_out + (size_t)T * NEXP;

    const size_t limb = (size_t)128 * NEMBD * sizeof(f16);   // 512 KB
    if (ws_size >= 2 * limb) {
        f16* wt_hi = (f16*)d_ws;
        f16* wt_lo = wt_hi + (size_t)128 * NEMBD;
        build_wt<<<NCH, 256, 0, stream>>>(Wr, Wn, wt_hi, wt_lo);
        router_fused3<<<T / BM, 256, 0, stream>>>(
            x, ep, wt_hi, wt_lo, br, bn, out_r, out_idx);
    } else {
        router_fused_f32<<<T / 64, 256, 0, stream>>>(
            x, ep, Wr, br, Wn, bn, out_r, out_idx);
    }
}

// Round 6
// 64.812 us; speedup vs baseline: 1.7132x; 1.7132x over previous
//
#include <hip/hip_runtime.h>
#include <math.h>

// NoisyTopKRouter via f16 2-limb (Markidis) 3-pass MFMA.
// Round 6: mega-chunk staging. BK=128 per LDS buffer (x staged as f16 limbs,
// split once at staging), 16 barriers total. B direct global->VGPR (L2-hot,
// 1-subchunk-ahead rotation). BM=64, 512 threads, grid=256.

typedef _Float16 f16;
typedef _Float16 f16x4 __attribute__((ext_vector_type(4)));
typedef _Float16 f16x8 __attribute__((ext_vector_type(8)));
typedef float    f32x4 __attribute__((ext_vector_type(4)));

#define NEMBD 2048
#define NEXP  64
#define BM    64
#define XSTR  136             // f16 row stride for 128-k mega rows (16B-aligned)
#define WSCALE 64.0f
#define INV_WSCALE 0.015625f

union F4H8 { float4 f; f16x8 h; };

__device__ __forceinline__ f16x8 ld16h(const f16* p) {
    F4H8 u; u.f = *(const float4*)p; return u.h;
}

// ---------- kernel 0: W -> transposed, x64-scaled f16 limbs ----------
// wt layout per limb: [chunk 64][n 128][k 32] f16 (n: 0..63 route, 64..127 noise)
__global__ __launch_bounds__(256) void build_wt(
    const float* __restrict__ Wr, const float* __restrict__ Wn,
    f16* __restrict__ wt_hi, f16* __restrict__ wt_lo)
{
    __shared__ float ws[32][129];
    const int c = blockIdx.x, t = threadIdx.x;
    const int k0 = c * 32;
    {
        const int k  = t >> 3;
        const int n8 = (t & 7) << 3;
        const float* s0 = Wr + (size_t)(k0 + k) * NEXP + n8;
        const float* s1 = Wn + (size_t)(k0 + k) * NEXP + n8;
        #pragma unroll
        for (int j = 0; j < 8; ++j) ws[k][n8 + j] = s0[j];
        #pragma unroll
        for (int j = 0; j < 8; ++j) ws[k][64 + n8 + j] = s1[j];
    }
    __syncthreads();
    {
        const int n  = t >> 1;           // 0..127
        const int kh = (t & 1) << 4;     // 0 or 16
        f16x8 hv0, hv1, lv0, lv1;
        #pragma unroll
        for (int j = 0; j < 8; ++j) {
            const float v = ws[kh + j][n] * WSCALE;
            const f16 h = (f16)v;
            hv0[j] = h; lv0[j] = (f16)(v - (float)h);
        }
        #pragma unroll
        for (int j = 0; j < 8; ++j) {
            const float v = ws[kh + 8 + j][n] * WSCALE;
            const f16 h = (f16)v;
            hv1[j] = h; lv1[j] = (f16)(v - (float)h);
        }
        const size_t base = ((size_t)c * 128 + n) * 32 + kh;
        *(f16x8*)(wt_hi + base)     = hv0;
        *(f16x8*)(wt_hi + base + 8) = hv1;
        *(f16x8*)(wt_lo + base)     = lv0;
        *(f16x8*)(wt_lo + base + 8) = lv1;
    }
}

// ---------- kernel 1: fused MFMA router, mega-chunk pipeline ----------
// 512 threads = 8 waves; wave w: rows (w&1)*32 (2 frags), cols (w>>1)*32 (2 frags)
__global__ __launch_bounds__(512, 2) void router_fused4(
    const float* __restrict__ x, const float* __restrict__ eps,
    const f16* __restrict__ wt_hi, const f16* __restrict__ wt_lo,
    const float* __restrict__ br, const float* __restrict__ bn,
    float* __restrict__ out_r, float* __restrict__ out_idx)
{
    // XH[2][64][136] f16, XL[2][64][136] f16  (69,632 B total)
    __shared__ __align__(16) f16 SH[4 * 8704];
    f16* XH = SH;                       // 2 buffers of 8704 f16
    f16* XL = SH + 2 * 8704;
    float* LG = (float*)SH;             // [128][65] f32 overlay (epilogue)
    float* TK = (float*)(SH + 2 * 8704);// [4][64] overlay

    const int tid  = threadIdx.x;
    const int lane = tid & 63;
    const int w    = tid >> 6;
    const int wr   = w & 1;             // row group (32 tokens)
    const int wc   = w >> 1;            // col group (32 cols)
    const int m0   = blockIdx.x * BM;

    // staging map: thread -> row=tid>>3 (0..63), kbase=(tid&7)*4; 4 float4 / mega
    const int srow  = tid >> 3;
    const int kbase = (tid & 7) << 2;
    const float* xsrc = x + (size_t)(m0 + srow) * NEMBD + kbase;
    const int xwoff = srow * XSTR + kbase;

    // A fragments
    const int row16 = lane & 15;
    const int kgrp  = (lane >> 4) << 3;            // 0,8,16,24
    const int arow0 = wr * 32 + row16;
    const int aoff0 = arow0 * XSTR;
    const int aoff1 = (arow0 + 16) * XSTR;

    // B fragments (direct global from wt limbs)
    const int boff0 = (wc * 32 + row16) * 32 + kgrp;
    const int boff1 = (wc * 32 + 16 + row16) * 32 + kgrp;

    f32x4 acc00 = {0.f,0.f,0.f,0.f}, acc01 = {0.f,0.f,0.f,0.f};
    f32x4 acc10 = {0.f,0.f,0.f,0.f}, acc11 = {0.f,0.f,0.f,0.f};
    f16x8 pAh0, pAh1, pAl0, pAl1, pBh0, pBh1, pBl0, pBl1;
    f16x8 ah0, ah1, al0, al1;
    float4 st0, st1, st2, st3;

#define BLOAD(S, g) do { const size_t cb = (size_t)(g) * 4096; \
    S##h0 = ld16h(wt_hi + cb + boff0); S##h1 = ld16h(wt_hi + cb + boff1); \
    S##l0 = ld16h(wt_lo + cb + boff0); S##l1 = ld16h(wt_lo + cb + boff1); } while (0)

#define AREAD(XHb, XLb, sc) do { const int ab = (sc) * 32 + kgrp; \
    ah0 = *(const f16x8*)((XHb) + aoff0 + ab); al0 = *(const f16x8*)((XLb) + aoff0 + ab); \
    ah1 = *(const f16x8*)((XHb) + aoff1 + ab); al1 = *(const f16x8*)((XLb) + aoff1 + ab); } while (0)

#define MFMA3(A, xh, xl, bh, bl) do { \
    A = __builtin_amdgcn_mfma_f32_16x16x32_f16(xh, bh, A, 0, 0, 0); \
    A = __builtin_amdgcn_mfma_f32_16x16x32_f16(xl, bh, A, 0, 0, 0); \
    A = __builtin_amdgcn_mfma_f32_16x16x32_f16(xh, bl, A, 0, 0, 0); } while (0)

#define MFMA12(S) do { \
    MFMA3(acc00, ah0, al0, S##h0, S##l0); \
    MFMA3(acc01, ah0, al0, S##h1, S##l1); \
    MFMA3(acc10, ah1, al1, S##h0, S##l0); \
    MFMA3(acc11, ah1, al1, S##h1, S##l1); } while (0)

#define WSPLIT(stv, XHw, XLw, i) do { \
    f16x4 hi_, lo_; \
    hi_[0] = (f16)stv.x; lo_[0] = (f16)(stv.x - (float)hi_[0]); \
    hi_[1] = (f16)stv.y; lo_[1] = (f16)(stv.y - (float)hi_[1]); \
    hi_[2] = (f16)stv.z; lo_[2] = (f16)(stv.z - (float)hi_[2]); \
    hi_[3] = (f16)stv.w; lo_[3] = (f16)(stv.w - (float)hi_[3]); \
    *(f16x4*)((XHw) + xwoff + 32 * (i)) = hi_; \
    *(f16x4*)((XLw) + xwoff + 32 * (i)) = lo_; } while (0)

    // ---- prologue: stage mega 0 into buf 0, preload B(0) ----
    st0 = *(const float4*)(xsrc);
    st1 = *(const float4*)(xsrc + 32);
    st2 = *(const float4*)(xsrc + 64);
    st3 = *(const float4*)(xsrc + 96);
    BLOAD(pA, 0);
    WSPLIT(st0, XH, XL, 0);
    WSPLIT(st1, XH, XL, 1);
    WSPLIT(st2, XH, XL, 2);
    WSPLIT(st3, XH, XL, 3);
    __syncthreads();

    // ---- main loop: 16 mega-chunks of 128 K ----
    for (int mc = 0; mc < 16; ++mc) {
        const int g0 = mc << 2;
        const int buf = mc & 1;
        const f16* XHb = XH + buf * 8704;
        const f16* XLb = XL + buf * 8704;
        f16* XHw = XH + (buf ^ 1) * 8704;
        f16* XLw = XL + (buf ^ 1) * 8704;
        const bool stage = (mc < 15);

        if (stage) {  // issue next mega's x loads early
            const float* s = xsrc + (mc + 1) * 128;
            st0 = *(const float4*)(s);
            st1 = *(const float4*)(s + 32);
            st2 = *(const float4*)(s + 64);
            st3 = *(const float4*)(s + 96);
            __builtin_amdgcn_sched_barrier(0);  // keep issue-early
        }

        BLOAD(pB, g0 + 1); AREAD(XHb, XLb, 0); MFMA12(pA);
        BLOAD(pA, g0 + 2); AREAD(XHb, XLb, 1); MFMA12(pB);
        BLOAD(pB, g0 + 3); AREAD(XHb, XLb, 2); MFMA12(pA);
        if (stage) { BLOAD(pA, g0 + 4); }
        AREAD(XHb, XLb, 3); MFMA12(pB);

        if (stage) {  // write-late: split + ds_write into other buffer
            WSPLIT(st0, XHw, XLw, 0);
            WSPLIT(st1, XHw, XLw, 1);
            WSPLIT(st2, XHw, XLw, 2);
            WSPLIT(st3, XHw, XLw, 3);
        }
        __syncthreads();
    }

#undef BLOAD
#undef AREAD
#undef MFMA3
#undef MFMA12
#undef WSPLIT

    // ---- epilogue: descale + bias, logits -> LDS overlay ----
    {
        const int tokb = wr * 32 + ((lane >> 4) << 2);
        #pragma unroll
        for (int fj = 0; fj < 4; ++fj) {
            const int f = fj >> 1, j = fj & 1;
            const int col = wc * 32 + j * 16 + row16;
            const float bias = (col < NEXP) ? br[col] : bn[col - NEXP];
            const f32x4 a = (fj == 0) ? acc00 : (fj == 1) ? acc01 : (fj == 2) ? acc10 : acc11;
            #pragma unroll
            for (int r = 0; r < 4; ++r)
                LG[col * 65 + tokb + f * 16 + r] = a[r] * INV_WSCALE + bias;
        }
    }
    __syncthreads();

    // ---- top-2: 2 lanes per token, each scans 32 experts, shfl merge ----
    if (tid < 128) {
        const int t = tid >> 1;
        const int h = tid & 1;
        const float* ep = eps + (size_t)(m0 + t) * NEXP;
        float v1 = -1e30f, v2 = -1e30f;
        int i1 = 0, i2 = 0;
        for (int j = 0; j < 32; ++j) {
            const int e = h * 32 + j;
            const float r  = LG[e * 65 + t];
            const float nr = LG[(NEXP + e) * 65 + t];
            const float sp = fmaxf(nr, 0.f) + log1pf(expf(-fabsf(nr)));
            const float noisy = fmaf(ep[e], sp, r);
            if (noisy > v1) { v2 = v1; i2 = i1; v1 = noisy; i1 = e; }
            else if (noisy > v2) { v2 = noisy; i2 = e; }
        }
        const float ov1 = __shfl_xor(v1, 1);
        const float ov2 = __shfl_xor(v2, 1);
        const int   oi1 = __shfl_xor(i1, 1);
        const int   oi2 = __shfl_xor(i2, 1);
        // a = experts 0..31 half, b = 32..63 half; ties prefer lower index
        float a1, a2, bb1, bb2; int ai1, ai2, bj1, bj2;
        if (h) { a1 = ov1; a2 = ov2; ai1 = oi1; ai2 = oi2; bb1 = v1;  bb2 = v2;  bj1 = i1;  bj2 = i2; }
        else   { a1 = v1;  a2 = v2;  ai1 = i1;  ai2 = i2;  bb1 = ov1; bb2 = ov2; bj1 = oi1; bj2 = oi2; }
        float t1, t2; int ti1, ti2;
        if (bb1 > a1) {
            t1 = bb1; ti1 = bj1;
            if (a1 >= bb2) { t2 = a1; ti2 = ai1; } else { t2 = bb2; ti2 = bj2; }
        } else {
            t1 = a1; ti1 = ai1;
            if (bb1 > a2) { t2 = bb1; ti2 = bj1; } else { t2 = a2; ti2 = ai2; }
        }
        if (h == 0) {
            const float e2 = expf(t2 - t1);
            const float p1 = 1.f / (1.f + e2);
            TK[0 * 64 + t] = p1;
            TK[1 * 64 + t] = e2 * p1;
            TK[2 * 64 + t] = (float)ti1;
            TK[3 * 64 + t] = (float)ti2;
        }
    }
    __syncthreads();

    // ---- write r_out coalesced (8 floats/thread) ----
    {
        const int t  = tid >> 3;            // 0..63
        const int c8 = (tid & 7) << 3;      // 0..56
        const float p1 = TK[t], p2 = TK[64 + t];
        const int i1 = (int)TK[128 + t], i2 = (int)TK[192 + t];
        float buf[8];
        #pragma unroll
        for (int jj = 0; jj < 8; ++jj) {
            const int e = c8 + jj;
            buf[jj] = (e == i1) ? p1 : (e == i2) ? p2 : 0.f;
        }
        float* dst = out_r + (size_t)(m0 + t) * NEXP + c8;
        *(float4*)(dst + 0) = *(float4*)(buf + 0);
        *(float4*)(dst + 4) = *(float4*)(buf + 4);
    }
    if (tid < BM) {
        float2 v = make_float2(TK[128 + tid], TK[192 + tid]);
        *(float2*)(out_idx + (size_t)(m0 + tid) * 2) = v;
    }
}

// ---------- fallback: fused f32 kernel (insurance only) ----------
__global__ __launch_bounds__(256) void router_fused_f32(
    const float* __restrict__ x, const float* __restrict__ eps,
    const float* __restrict__ Wr, const float* __restrict__ br,
    const float* __restrict__ Wn, const float* __restrict__ bn,
    float* __restrict__ out_r, float* __restrict__ out_idx)
{
    __shared__ float xs[32][64];
    __shared__ float ws2[32][128];
    __shared__ float lg[128][64];
    __shared__ float tk[4][64];
    const int tid = threadIdx.x;
    const int tx = tid & 15, ty = tid >> 4;
    const int m0 = blockIdx.x * 64;
    float acc[4][8];
    #pragma unroll
    for (int i = 0; i < 4; ++i)
        #pragma unroll
        for (int j = 0; j < 8; ++j) acc[i][j] = 0.f;
    for (int kc = 0; kc < NEMBD; kc += 32) {
        {
            const int tm = tid >> 2, kk = (tid & 3) << 3;
            const float* src = x + (size_t)(m0 + tm) * NEMBD + kc + kk;
            const float4 a = *(const float4*)(src);
            const float4 b = *(const float4*)(src + 4);
            xs[kk+0][tm]=a.x; xs[kk+1][tm]=a.y; xs[kk+2][tm]=a.z; xs[kk+3][tm]=a.w;
            xs[kk+4][tm]=b.x; xs[kk+5][tm]=b.y; xs[kk+6][tm]=b.z; xs[kk+7][tm]=b.w;
        }
        {
            const int kr = tid >> 3, q = tid & 7;
            const float* src = (q < 4)
                ? (Wr + (size_t)(kc + kr) * NEXP + (q << 4))
                : (Wn + (size_t)(kc + kr) * NEXP + ((q - 4) << 4));
            float* dst = &ws2[kr][q << 4];
            #pragma unroll
            for (int j = 0; j < 16; ++j) dst[j] = src[j];
        }
        __syncthreads();
        #pragma unroll
        for (int k = 0; k < 32; ++k) {
            const float4 xv = *(const float4*)&xs[k][ty << 2];
            const float4 wa = *(const float4*)&ws2[k][tx << 3];
            const float4 wb = *(const float4*)&ws2[k][(tx << 3) + 4];
            const float xr[4] = {xv.x, xv.y, xv.z, xv.w};
            const float wcx[8] = {wa.x, wa.y, wa.z, wa.w, wb.x, wb.y, wb.z, wb.w};
            #pragma unroll
            for (int i = 0; i < 4; ++i)
                #pragma unroll
                for (int j = 0; j < 8; ++j)
                    acc[i][j] = fmaf(xr[i], wcx[j], acc[i][j]);
        }
        __syncthreads();
    }
    {
        const int n0 = tx << 3;
        #pragma unroll
        for (int j = 0; j < 8; ++j) {
            const int n = n0 + j;
            const float b = (n < NEXP) ? br[n] : bn[n - NEXP];
            #pragma unroll
            for (int i = 0; i < 4; ++i)
                lg[n][(ty << 2) + i] = acc[i][j] + b;
        }
    }
    __syncthreads();
    if (tid < 64) {
        const int t = tid;
        const float* ep = eps + (size_t)(m0 + t) * NEXP;
        float v1 = -1e30f, v2 = -1e30f; int i1 = 0, i2 = 0;
        for (int e = 0; e < NEXP; ++e) {
            const float r = lg[e][t], nr = lg[NEXP + e][t];
            const float sp = fmaxf(nr, 0.f) + log1pf(expf(-fabsf(nr)));
            const float noisy = fmaf(ep[e], sp, r);
            if (noisy > v1) { v2=v1; i2=i1; v1=noisy; i1=e; }
            else if (noisy > v2) { v2=noisy; i2=e; }
        }
        const float e2 = expf(v2 - v1);
        const float p1 = 1.f / (1.f + e2);
        tk[0][t]=p1; tk[1][t]=e2*p1; tk[2][t]=(float)i1; tk[3][t]=(float)i2;
    }
    __syncthreads();
    {
        const int t = tid >> 2, c = tid & 3;
        const float p1 = tk[0][t], p2 = tk[1][t];
        const int i1 = (int)tk[2][t], i2 = (int)tk[3][t];
        float buf[16];
        #pragma unroll
        for (int j = 0; j < 16; ++j) {
            const int e = (c << 4) + j;
            buf[j] = (e == i1) ? p1 : (e == i2) ? p2 : 0.f;
        }
        float* dst = out_r + (size_t)(m0 + t) * NEXP + (c << 4);
        *(float4*)(dst+0)=*(float4*)(buf+0); *(float4*)(dst+4)=*(float4*)(buf+4);
        *(float4*)(dst+8)=*(float4*)(buf+8); *(float4*)(dst+12)=*(float4*)(buf+12);
    }
    if (tid < 64) {
        float2 v = make_float2(tk[2][tid], tk[3][tid]);
        *(float2*)(out_idx + (size_t)(m0 + tid) * 2) = v;
    }
}

extern "C" void kernel_launch(void* const* d_in, const int* in_sizes, int n_in,
                              void* d_out, int out_size, void* d_ws, size_t ws_size,
                              hipStream_t stream) {
    const float* x  = (const float*)d_in[0];
    const float* ep = (const float*)d_in[1];
    const float* Wr = (const float*)d_in[2];
    const float* br = (const float*)d_in[3];
    const float* Wn = (const float*)d_in[4];
    const float* bn = (const float*)d_in[5];

    const int T = in_sizes[1] / NEXP;
    float* out_r   = (float*)d_out;
    float* out_idx = (float*)d_out + (size_t)T * NEXP;

    const size_t limb = (size_t)128 * NEMBD * sizeof(f16);   // 512 KB
    if (ws_size >= 2 * limb) {
        f16* wt_hi = (f16*)d_ws;
        f16* wt_lo = wt_hi + (size_t)128 * NEMBD;
        build_wt<<<64, 256, 0, stream>>>(Wr, Wn, wt_hi, wt_lo);
        router_fused4<<<T / BM, 512, 0, stream>>>(
            x, ep, wt_hi, wt_lo, br, bn, out_r, out_idx);
    } else {
        router_fused_f32<<<T / 64, 256, 0, stream>>>(
            x, ep, Wr, br, Wn, bn, out_r, out_idx);
    }
}